// Round 1
// baseline (415.625 us; speedup 1.0000x reference)
//
#include <hip/hip_runtime.h>

#define PPn 8192
#define KKn 20
#define KPn (PPn*KKn)
constexpr float EPS_ = 1e-5f;

// ---- ws layout (float offsets) ----
constexpr size_t OFF_F0   = 0;              // 8192*64
constexpr size_t OFF_IDX  = 524288;         // 8192*20 (int)
constexpr size_t OFF_XYZ  = 688128;         // 8192*20*6
constexpr size_t OFF_HM   = 1671168;        // 160*42
constexpr size_t OFF_B1P  = 1677888;        // 32*64*2
constexpr size_t OFF_W    = 1681984;        // 8192*512
constexpr size_t OFF_A2   = 5876288;        // 8192*64
constexpr size_t OFF_A3   = 6400576;        // 8192*64
constexpr size_t OFF_A4   = 6924864;        // 8192*128
constexpr size_t OFF_P2   = 7973440;        // 128*64*2
constexpr size_t OFF_P3   = 7989824;        // 128*64*2
constexpr size_t OFF_P4   = 8006208;        // 128*128*2
constexpr size_t OFF_P5   = 8038976;        // 128*1024*2
constexpr size_t OFF_MX5  = 8301120;        // 128*1024
constexpr size_t OFF_M5   = 8432192;        // 128*1024 repacked conv5_w
constexpr size_t OFF_POOL = 8563264;        // 8*1024
constexpr size_t OFF_A6   = 8571456;        // 8*512

__device__ __forceinline__ float wredf(float v) {
  #pragma unroll
  for (int o = 32; o > 0; o >>= 1) v += __shfl_xor(v, o, 64);
  return v;
}
__device__ __forceinline__ int wredi(int v) {
  #pragma unroll
  for (int o = 32; o > 0; o >>= 1) v += __shfl_xor(v, o, 64);
  return v;
}
__device__ __forceinline__ int wmini(int v) {
  #pragma unroll
  for (int o = 32; o > 0; o >>= 1) v = min(v, __shfl_xor(v, o, 64));
  return v;
}

// ---------------- KNN + xyz + f0pre ----------------
__global__ __launch_bounds__(256) void k_prep(const float* __restrict__ x,
    const float* __restrict__ c1w, int* __restrict__ idxg,
    float* __restrict__ xyz, float* __restrict__ f0)
{
  __shared__ float4 pts4[1024];
  int tid = threadIdx.x;
  int b = blockIdx.x >> 8;
  int wid = tid >> 6, lane = tid & 63;
  for (int i = tid; i < 1024; i += 256) {
    float px = x[(b*3+0)*1024 + i];
    float py = x[(b*3+1)*1024 + i];
    float pz = x[(b*3+2)*1024 + i];
    pts4[i] = make_float4(px, py, pz, px*px + py*py + pz*pz);
  }
  __syncthreads();
  int nq = ((blockIdx.x & 255) << 2) + wid;
  float4 q = pts4[nq];
  int qrow = b*1024 + nq;
  {
    float w0 = c1w[lane*3+0], w1 = c1w[lane*3+1], w2 = c1w[lane*3+2];
    f0[(size_t)qrow*64 + lane] = q.x*w0 + q.y*w1 + q.z*w2;
  }
  unsigned int uk[16];
  #pragma unroll
  for (int i = 0; i < 16; ++i) {
    float4 pm = pts4[i*64 + lane];
    float d = 2.f*(q.x*pm.x + q.y*pm.y + q.z*pm.z) - q.w - pm.w;
    unsigned int bits = __float_as_uint(d);
    uk[i] = bits ^ ((bits & 0x80000000u) ? 0xFFFFFFFFu : 0x80000000u);
  }
  // binary search for 20th-largest key V
  unsigned int lo = 0u, hi = 0xFFFFFFFFu;
  while (lo < hi) {
    unsigned int mid = lo + ((hi - lo) >> 1);
    int cnt = 0;
    #pragma unroll
    for (int i = 0; i < 16; ++i) cnt += (uk[i] > mid) ? 1 : 0;
    cnt = wredi(cnt);
    if (cnt <= 19) hi = mid; else lo = mid + 1u;
  }
  unsigned int V = lo;
  unsigned int sel = 0; int cg = 0;
  #pragma unroll
  for (int i = 0; i < 16; ++i) if (uk[i] > V) { sel |= (1u << i); ++cg; }
  cg = wredi(cg);
  int r = 20 - cg;            // #equals to take, smallest index first (jax tie rule)
  unsigned int taken = 0;
  while (r > 0) {
    int jm = 0x7FFFFFFF;
    #pragma unroll
    for (int i = 0; i < 16; ++i)
      if ((uk[i] == V) && !((taken >> i) & 1u) && jm == 0x7FFFFFFF) jm = i*64 + lane;
    int jw = wmini(jm);
    if ((jw & 63) == lane) { int ii = jw >> 6; taken |= (1u << ii); sel |= (1u << ii); }
    --r;
  }
  int cl = __popc(sel);
  int pre = cl;
  #pragma unroll
  for (int o = 1; o < 64; o <<= 1) { int t = __shfl_up(pre, o, 64); if (lane >= o) pre += t; }
  int slot = pre - cl;
  #pragma unroll
  for (int i = 0; i < 16; ++i) {
    if ((sel >> i) & 1u) {
      int j = i*64 + lane;
      idxg[qrow*20 + slot] = b*1024 + j;
      float4 pm = pts4[j];
      float* xr = xyz + (size_t)(qrow*20 + slot)*6;
      xr[0] = pm.x - q.x; xr[1] = pm.y - q.y; xr[2] = pm.z - q.z;
      xr[3] = pm.x; xr[4] = pm.y; xr[5] = pm.z;
      ++slot;
    }
  }
}

// ---------------- repack conv5_w: m5[k][o] = w[o*128+k] ----------------
__global__ __launch_bounds__(256) void k_repack(const float* __restrict__ w, float* __restrict__ m5)
{
  int idx = blockIdx.x*256 + threadIdx.x;   // 131072
  int k = idx >> 10, o = idx & 1023;
  m5[idx] = w[o*128 + k];
}

// ---------------- stats: xyz moments (blocks 0..159) + bn1 partials (160..191) ----------------
__global__ __launch_bounds__(256) void k_stats(const float* __restrict__ xyz,
    const float* __restrict__ f0, float* __restrict__ hMom, float* __restrict__ b1P)
{
  __shared__ float lred[512];
  int tid = threadIdx.x, blk = blockIdx.x;
  int wid = tid >> 6, lane = tid & 63;
  if (blk < 160) {
    float m1[6] = {0,0,0,0,0,0};
    float m2[36];
    #pragma unroll
    for (int i = 0; i < 36; ++i) m2[i] = 0.f;
    for (int it = 0; it < 4; ++it) {
      size_t rr = (size_t)blk*1024 + it*256 + tid;
      const float* xr = xyz + rr*6;
      float v[6];
      #pragma unroll
      for (int d = 0; d < 6; ++d) v[d] = xr[d];
      #pragma unroll
      for (int d = 0; d < 6; ++d) {
        m1[d] += v[d];
        #pragma unroll
        for (int e = 0; e < 6; ++e) m2[d*6+e] += v[d]*v[e];
      }
    }
    #pragma unroll
    for (int i = 0; i < 6; ++i) m1[i] = wredf(m1[i]);
    #pragma unroll
    for (int i = 0; i < 36; ++i) m2[i] = wredf(m2[i]);
    if (lane == 0) {
      #pragma unroll
      for (int i = 0; i < 6; ++i) lred[wid*42 + i] = m1[i];
      #pragma unroll
      for (int i = 0; i < 36; ++i) lred[wid*42 + 6 + i] = m2[i];
    }
    __syncthreads();
    if (tid < 42) hMom[blk*42 + tid] = lred[tid] + lred[42+tid] + lred[84+tid] + lred[126+tid];
  } else {
    int pb = blk - 160;
    int c = tid & 63, rq = tid >> 6;
    float s = 0.f, qq = 0.f;
    for (int rr = 0; rr < 64; ++rr) {
      float v = f0[((size_t)(pb*256 + rq*64 + rr))*64 + c];
      s += v; qq += v*v;
    }
    lred[rq*128 + c*2] = s; lred[rq*128 + c*2 + 1] = qq;
    __syncthreads();
    if (tid < 128) b1P[pb*128 + tid] = lred[tid] + lred[128+tid] + lred[256+tid] + lred[384+tid];
  }
}

// ---------------- W-build: scorenet + gather(prev feat w/ bn+relu) ----------------
__global__ __launch_bounds__(256) void k_wbuild(
    const float* __restrict__ xyz, const int* __restrict__ idxg,
    const float* __restrict__ aprev, const float* __restrict__ hMom,
    const float* __restrict__ prevPart, int nPB,
    const float* __restrict__ w1, const float* __restrict__ sg, const float* __restrict__ sb,
    const float* __restrict__ w2, const float* __restrict__ b2,
    const float* __restrict__ bng, const float* __restrict__ bnb,
    float* __restrict__ Wo)
{
  __shared__ float momS[42], sSc[16], sSh[16], pSc[64], pSh[64];
  __shared__ float scoreS[4][20][8];
  int tid = threadIdx.x;
  if (tid < 42) {
    float s = 0.f;
    for (int pb = 0; pb < 160; ++pb) s += hMom[pb*42 + tid];
    momS[tid] = s;
  }
  if (tid >= 64 && tid < 128) {
    int c = tid - 64;
    float s = 0.f, qq = 0.f;
    for (int p = 0; p < nPB; ++p) { s += prevPart[(p*64 + c)*2]; qq += prevPart[(p*64 + c)*2 + 1]; }
    float mu = s / 8192.f;
    float var = qq / 8192.f - mu*mu;
    float rst = rsqrtf(var + EPS_);
    float g = bng[c];
    pSc[c] = g*rst; pSh[c] = bnb[c] - mu*g*rst;
  }
  __syncthreads();
  if (tid < 16) {
    float wv[6];
    #pragma unroll
    for (int d = 0; d < 6; ++d) wv[d] = w1[tid*6 + d];
    float mu = 0.f, E2 = 0.f;
    #pragma unroll
    for (int d = 0; d < 6; ++d) mu += wv[d]*(momS[d] / (float)KPn);
    #pragma unroll
    for (int d = 0; d < 6; ++d) {
      float qd = 0.f;
      #pragma unroll
      for (int e = 0; e < 6; ++e) qd += (momS[6 + d*6 + e] / (float)KPn)*wv[e];
      E2 += wv[d]*qd;
    }
    float var = E2 - mu*mu;
    float rst = rsqrtf(var + EPS_);
    float g = sg[tid];
    sSc[tid] = g*rst; sSh[tid] = sb[tid] - mu*g*rst;
  }
  __syncthreads();
  if (tid < 80) {
    int pl = tid / 20, k2 = tid % 20;
    int p = blockIdx.x*4 + pl;
    const float* xr = xyz + (size_t)(p*20 + k2)*6;
    float v0=xr[0],v1=xr[1],v2=xr[2],v3=xr[3],v4=xr[4],v5=xr[5];
    float hb[16];
    #pragma unroll
    for (int c = 0; c < 16; ++c) {
      float h = v0*w1[c*6+0]+v1*w1[c*6+1]+v2*w1[c*6+2]+v3*w1[c*6+3]+v4*w1[c*6+4]+v5*w1[c*6+5];
      hb[c] = fmaxf(0.f, h*sSc[c] + sSh[c]);
    }
    float lg[8]; float mx = -3.4e38f;
    #pragma unroll
    for (int m = 0; m < 8; ++m) {
      float s = b2[m];
      #pragma unroll
      for (int c = 0; c < 16; ++c) s += hb[c]*w2[m*16+c];
      lg[m] = s; mx = fmaxf(mx, s);
    }
    float den = 0.f;
    #pragma unroll
    for (int m = 0; m < 8; ++m) { lg[m] = expf(lg[m]-mx); den += lg[m]; }
    #pragma unroll
    for (int m = 0; m < 8; ++m) scoreS[pl][k2][m] = lg[m]/den;
  }
  __syncthreads();
  int wid = tid >> 6, lane = tid & 63;
  int p = blockIdx.x*4 + wid;
  float ps = pSc[lane], ph = pSh[lane];
  float acc[8];
  #pragma unroll
  for (int m = 0; m < 8; ++m) acc[m] = 0.f;
  const int* ip = idxg + p*20;
  for (int k = 0; k < 20; ++k) {
    int j = ip[k];
    float v = aprev[(size_t)j*64 + lane];
    v = fmaxf(0.f, v*ps + ph);
    #pragma unroll
    for (int m = 0; m < 8; ++m) acc[m] += scoreS[wid][k][m]*v;
  }
  #pragma unroll
  for (int m = 0; m < 8; ++m) Wo[(size_t)p*512 + m*64 + lane] = acc[m];
}

// ---------------- generic tiled GEMM (64 rows x CT cols per block) ----------------
template<int KD, int CO, int CT, int BMODE, bool BNA, bool DOMAX, bool WRITEC>
__global__ __launch_bounds__(256) void k_gemm(
    const float* __restrict__ A, const float* __restrict__ Bsrc, float* __restrict__ C,
    const float* __restrict__ aPart, const float* __restrict__ abng, const float* __restrict__ abnb,
    float* __restrict__ outPart, float* __restrict__ outMax)
{
  constexpr int TJ = CT/16;
  __shared__ __align__(16) float As[64*64];
  __shared__ __align__(16) float Bs[64*CT];
  __shared__ float aSc[128], aSh[128];
  int tid = threadIdx.x;
  int rb = blockIdx.x, gy = blockIdx.y;
  if constexpr (BNA) {
    if (tid < KD) {
      float s = 0.f, qq = 0.f;
      for (int p = 0; p < 128; ++p) { s += aPart[(p*KD + tid)*2]; qq += aPart[(p*KD + tid)*2 + 1]; }
      float mu = s / 8192.f;
      float var = qq / 8192.f - mu*mu;
      float rst = rsqrtf(var + EPS_);
      float g = abng[tid];
      aSc[tid] = g*rst; aSh[tid] = abnb[tid] - mu*g*rst;
    }
    __syncthreads();
  }
  float acc[4][TJ];
  #pragma unroll
  for (int i = 0; i < 4; ++i)
    #pragma unroll
    for (int j = 0; j < TJ; ++j) acc[i][j] = 0.f;
  int pg = tid >> 4, cgi = tid & 15;
  for (int kc = 0; kc < KD/64; ++kc) {
    {
      int row = tid >> 2, kq = tid & 3;
      const float* ap = A + (size_t)(rb*64 + row)*KD + kc*64 + kq*16;
      #pragma unroll
      for (int u = 0; u < 4; ++u) {
        float4 v = *(const float4*)(ap + u*4);
        int k0 = kq*16 + u*4;
        if constexpr (BNA) {
          int kb = kc*64 + k0;
          v.x = fmaxf(0.f, v.x*aSc[kb+0] + aSh[kb+0]);
          v.y = fmaxf(0.f, v.y*aSc[kb+1] + aSh[kb+1]);
          v.z = fmaxf(0.f, v.z*aSc[kb+2] + aSh[kb+2]);
          v.w = fmaxf(0.f, v.w*aSc[kb+3] + aSh[kb+3]);
        }
        As[(k0+0)*64 + row] = v.x;
        As[(k0+1)*64 + row] = v.y;
        As[(k0+2)*64 + row] = v.z;
        As[(k0+3)*64 + row] = v.w;
      }
    }
    {
      #pragma unroll
      for (int pass = 0; pass < CT/16; ++pass) {
        int f = pass*256 + tid;
        int kk = f / (CT/4);
        int oo = (f % (CT/4))*4;
        const float* bp;
        if constexpr (BMODE == 0) bp = Bsrc + (size_t)kk*(8*CO) + kc*CO + gy*CT + oo;
        else                      bp = Bsrc + (size_t)(kc*64 + kk)*CO + gy*CT + oo;
        *(float4*)(Bs + kk*CT + oo) = *(const float4*)bp;
      }
    }
    __syncthreads();
    #pragma unroll 4
    for (int kk = 0; kk < 64; ++kk) {
      float4 av = *(const float4*)(As + kk*64 + pg*4);
      #pragma unroll
      for (int j4 = 0; j4 < TJ/4; ++j4) {
        float4 bv = *(const float4*)(Bs + kk*CT + cgi*TJ + j4*4);
        acc[0][j4*4+0] += av.x*bv.x; acc[0][j4*4+1] += av.x*bv.y; acc[0][j4*4+2] += av.x*bv.z; acc[0][j4*4+3] += av.x*bv.w;
        acc[1][j4*4+0] += av.y*bv.x; acc[1][j4*4+1] += av.y*bv.y; acc[1][j4*4+2] += av.y*bv.z; acc[1][j4*4+3] += av.y*bv.w;
        acc[2][j4*4+0] += av.z*bv.x; acc[2][j4*4+1] += av.z*bv.y; acc[2][j4*4+2] += av.z*bv.z; acc[2][j4*4+3] += av.z*bv.w;
        acc[3][j4*4+0] += av.w*bv.x; acc[3][j4*4+1] += av.w*bv.y; acc[3][j4*4+2] += av.w*bv.z; acc[3][j4*4+3] += av.w*bv.w;
      }
    }
    __syncthreads();
  }
  if constexpr (WRITEC) {
    #pragma unroll
    for (int i = 0; i < 4; ++i) {
      size_t row = (size_t)rb*64 + pg*4 + i;
      #pragma unroll
      for (int j4 = 0; j4 < TJ/4; ++j4) {
        float4 v;
        v.x = acc[i][j4*4+0]; v.y = acc[i][j4*4+1]; v.z = acc[i][j4*4+2]; v.w = acc[i][j4*4+3];
        *(float4*)(C + row*CO + gy*CT + cgi*TJ + j4*4) = v;
      }
    }
  }
  float* red = As;   // As no longer needed
  #pragma unroll
  for (int j = 0; j < TJ; ++j)
    red[pg*CT + cgi*TJ + j] = acc[0][j]+acc[1][j]+acc[2][j]+acc[3][j];
  __syncthreads();
  if (tid < CT) {
    float t = 0.f;
    for (int p2 = 0; p2 < 16; ++p2) t += red[p2*CT + tid];
    outPart[((size_t)rb*CO + gy*CT + tid)*2] = t;
  }
  __syncthreads();
  #pragma unroll
  for (int j = 0; j < TJ; ++j)
    red[pg*CT + cgi*TJ + j] = acc[0][j]*acc[0][j]+acc[1][j]*acc[1][j]+acc[2][j]*acc[2][j]+acc[3][j]*acc[3][j];
  __syncthreads();
  if (tid < CT) {
    float t = 0.f;
    for (int p2 = 0; p2 < 16; ++p2) t += red[p2*CT + tid];
    outPart[((size_t)rb*CO + gy*CT + tid)*2 + 1] = t;
  }
  if constexpr (DOMAX) {
    __syncthreads();
    #pragma unroll
    for (int j = 0; j < TJ; ++j)
      red[pg*CT + cgi*TJ + j] = fmaxf(fmaxf(acc[0][j],acc[1][j]), fmaxf(acc[2][j],acc[3][j]));
    __syncthreads();
    if (tid < CT) {
      float t = -3.4e38f;
      for (int p2 = 0; p2 < 16; ++p2) t = fmaxf(t, red[p2*CT + tid]);
      outMax[(size_t)rb*CO + gy*CT + tid] = t;
    }
  }
}

// ---------------- bn5 + relu + maxpool over n ----------------
__global__ __launch_bounds__(256) void k_pool(const float* __restrict__ p5, const float* __restrict__ mx5,
    const float* __restrict__ g5, const float* __restrict__ b5, float* __restrict__ pool)
{
  int gid = blockIdx.x*256 + threadIdx.x;   // 8192
  int b = gid >> 10, ch = gid & 1023;
  float s = 0.f, qq = 0.f;
  for (int rb = 0; rb < 128; ++rb) {
    s  += p5[((size_t)rb*1024 + ch)*2];
    qq += p5[((size_t)rb*1024 + ch)*2 + 1];
  }
  float mu = s / 8192.f;
  float var = qq / 8192.f - mu*mu;
  float rst = rsqrtf(var + EPS_);
  float mx = -3.4e38f;
  for (int t = 0; t < 16; ++t) mx = fmaxf(mx, mx5[(size_t)(b*16 + t)*1024 + ch]);
  pool[gid] = fmaxf(0.f, g5[ch]*(mx - mu)*rst + b5[ch]);
}

// ---------------- lin1 ----------------
__global__ __launch_bounds__(256) void k_lin1(const float* __restrict__ pool,
    const float* __restrict__ w, float* __restrict__ a6)
{
  int idx = blockIdx.x*256 + threadIdx.x;   // 4096 = 8*512
  int r = idx >> 9, c = idx & 511;
  const float4* pr = (const float4*)(pool + r*1024);
  const float4* wr = (const float4*)(w + (size_t)c*1024);
  float s = 0.f;
  for (int t = 0; t < 256; ++t) {
    float4 a = pr[t], bb = wr[t];
    s += a.x*bb.x + a.y*bb.y + a.z*bb.z + a.w*bb.w;
  }
  a6[idx] = s;
}

// ---------------- bn6 + relu + lin2 + bias ----------------
__global__ __launch_bounds__(256) void k_head(const float* __restrict__ a6,
    const float* __restrict__ g6, const float* __restrict__ b6,
    const float* __restrict__ w2, const float* __restrict__ bb,
    float* __restrict__ out)
{
  __shared__ float f6[8*512];
  int tid = threadIdx.x;
  for (int c = tid; c < 512; c += 256) {
    float v[8]; float s = 0.f;
    #pragma unroll
    for (int r = 0; r < 8; ++r) { v[r] = a6[r*512 + c]; s += v[r]; }
    float mu = s / 8.f;
    float qq = 0.f;
    #pragma unroll
    for (int r = 0; r < 8; ++r) { float d = v[r] - mu; qq += d*d; }
    float var = qq / 8.f;
    float rst = rsqrtf(var + EPS_);
    float sc = g6[c]*rst, sh = b6[c] - mu*g6[c]*rst;
    #pragma unroll
    for (int r = 0; r < 8; ++r) f6[r*512 + c] = fmaxf(0.f, v[r]*sc + sh);
  }
  __syncthreads();
  for (int o = tid; o < 320; o += 256) {
    int r = o / 40, c2 = o % 40;
    float s = bb[c2];
    for (int k = 0; k < 512; ++k) s += f6[r*512 + k]*w2[c2*512 + k];
    out[o] = s;
  }
}

extern "C" void kernel_launch(void* const* d_in, const int* in_sizes, int n_in,
                              void* d_out, int out_size, void* d_ws, size_t ws_size,
                              hipStream_t stream) {
  (void)in_sizes; (void)n_in; (void)out_size; (void)ws_size;
  const float* x     = (const float*)d_in[0];
  const float* c1w   = (const float*)d_in[1];
  const float* bn1g  = (const float*)d_in[2];
  const float* bn1b  = (const float*)d_in[3];
  const float* mat2  = (const float*)d_in[4];
  const float* mat3  = (const float*)d_in[5];
  const float* mat4  = (const float*)d_in[6];
  const float* sn2w1 = (const float*)d_in[7];
  const float* sn2g  = (const float*)d_in[8];
  const float* sn2b  = (const float*)d_in[9];
  const float* sn2w2 = (const float*)d_in[10];
  const float* sn2b2 = (const float*)d_in[11];
  const float* sn3w1 = (const float*)d_in[12];
  const float* sn3g  = (const float*)d_in[13];
  const float* sn3b  = (const float*)d_in[14];
  const float* sn3w2 = (const float*)d_in[15];
  const float* sn3b2 = (const float*)d_in[16];
  const float* sn4w1 = (const float*)d_in[17];
  const float* sn4g  = (const float*)d_in[18];
  const float* sn4b  = (const float*)d_in[19];
  const float* sn4w2 = (const float*)d_in[20];
  const float* sn4b2 = (const float*)d_in[21];
  const float* bn2g  = (const float*)d_in[22];
  const float* bn2b  = (const float*)d_in[23];
  const float* bn3g  = (const float*)d_in[24];
  const float* bn3b  = (const float*)d_in[25];
  const float* bn4g  = (const float*)d_in[26];
  const float* bn4b  = (const float*)d_in[27];
  const float* c5w   = (const float*)d_in[28];
  const float* bn5g  = (const float*)d_in[29];
  const float* bn5b  = (const float*)d_in[30];
  const float* l1w   = (const float*)d_in[31];
  const float* bn6g  = (const float*)d_in[32];
  const float* bn6b  = (const float*)d_in[33];
  const float* l2w   = (const float*)d_in[34];
  const float* l2b   = (const float*)d_in[35];
  float* ws   = (float*)d_ws;
  float* f0   = ws + OFF_F0;
  int*   idxg = (int*)(ws + OFF_IDX);
  float* xyz  = ws + OFF_XYZ;
  float* hMom = ws + OFF_HM;
  float* b1P  = ws + OFF_B1P;
  float* W    = ws + OFF_W;
  float* a2   = ws + OFF_A2;
  float* a3   = ws + OFF_A3;
  float* a4   = ws + OFF_A4;
  float* p2   = ws + OFF_P2;
  float* p3   = ws + OFF_P3;
  float* p4   = ws + OFF_P4;
  float* p5   = ws + OFF_P5;
  float* mx5  = ws + OFF_MX5;
  float* m5   = ws + OFF_M5;
  float* pool = ws + OFF_POOL;
  float* a6   = ws + OFF_A6;
  float* out  = (float*)d_out;

  k_prep<<<2048, 256, 0, stream>>>(x, c1w, idxg, xyz, f0);
  k_repack<<<512, 256, 0, stream>>>(c5w, m5);
  k_stats<<<192, 256, 0, stream>>>(xyz, f0, hMom, b1P);

  k_wbuild<<<2048, 256, 0, stream>>>(xyz, idxg, f0, hMom, b1P, 32,
      sn2w1, sn2g, sn2b, sn2w2, sn2b2, bn1g, bn1b, W);
  k_gemm<512,64,64,0,false,false,true><<<dim3(128,1), 256, 0, stream>>>(
      W, mat2, a2, nullptr, nullptr, nullptr, p2, nullptr);

  k_wbuild<<<2048, 256, 0, stream>>>(xyz, idxg, a2, hMom, p2, 128,
      sn3w1, sn3g, sn3b, sn3w2, sn3b2, bn2g, bn2b, W);
  k_gemm<512,64,64,0,false,false,true><<<dim3(128,1), 256, 0, stream>>>(
      W, mat3, a3, nullptr, nullptr, nullptr, p3, nullptr);

  k_wbuild<<<2048, 256, 0, stream>>>(xyz, idxg, a3, hMom, p3, 128,
      sn4w1, sn4g, sn4b, sn4w2, sn4b2, bn3g, bn3b, W);
  k_gemm<512,128,128,0,false,false,true><<<dim3(128,1), 256, 0, stream>>>(
      W, mat4, a4, nullptr, nullptr, nullptr, p4, nullptr);

  k_gemm<128,1024,128,1,true,true,false><<<dim3(128,8), 256, 0, stream>>>(
      a4, m5, nullptr, p4, bn4g, bn4b, p5, mx5);

  k_pool<<<32, 256, 0, stream>>>(p5, mx5, bn5g, bn5b, pool);
  k_lin1<<<16, 256, 0, stream>>>(pool, l1w, a6);
  k_head<<<1, 256, 0, stream>>>(a6, bn6g, bn6b, l2w, l2b, out);
}

// Round 2
// 299.862 us; speedup vs baseline: 1.3861x; 1.3861x over previous
//
#include <hip/hip_runtime.h>

#define PPn 8192
#define KKn 20
#define KPn (PPn*KKn)
constexpr float EPS_ = 1e-5f;

// ---- ws layout (float offsets) ----
constexpr size_t OFF_F0   = 0;              // 8192*64
constexpr size_t OFF_IDX  = 524288;         // 8192*20 (int)
constexpr size_t OFF_XYZ  = 688128;         // 8192*20*6
constexpr size_t OFF_HM   = 1671168;        // 160*42
constexpr size_t OFF_B1P  = 1677888;        // 32*64*2
constexpr size_t OFF_MOM  = 1681984;        // 42 (pad 64)
constexpr size_t OFF_COEF = 1682048;        // 160 (pad 192)
constexpr size_t OFF_BN4C = 1682240;        // 256
constexpr size_t OFF_W    = 1682496;        // 8192*512
constexpr size_t OFF_A2   = 5876800;        // 8192*64
constexpr size_t OFF_A3   = 6401088;        // 8192*64
constexpr size_t OFF_A4   = 6925376;        // 8192*128
constexpr size_t OFF_P2   = 7973952;        // 128*64*2
constexpr size_t OFF_P3   = 7990336;        // 128*64*2
constexpr size_t OFF_P4   = 8006720;        // 128*128*2
constexpr size_t OFF_P5   = 8039488;        // 128*1024*2
constexpr size_t OFF_MX5  = 8301632;        // 128*1024
constexpr size_t OFF_M5   = 8432704;        // 128*1024 repacked conv5_w
constexpr size_t OFF_POOL = 8563776;        // 8*1024
constexpr size_t OFF_A6   = 8571968;        // 8*512

__device__ __forceinline__ float wredf(float v) {
  #pragma unroll
  for (int o = 32; o > 0; o >>= 1) v += __shfl_xor(v, o, 64);
  return v;
}
__device__ __forceinline__ int wredi(int v) {
  #pragma unroll
  for (int o = 32; o > 0; o >>= 1) v += __shfl_xor(v, o, 64);
  return v;
}
__device__ __forceinline__ int wmini(int v) {
  #pragma unroll
  for (int o = 32; o > 0; o >>= 1) v = min(v, __shfl_xor(v, o, 64));
  return v;
}

// ---------------- KNN + xyz + f0pre ----------------
__global__ __launch_bounds__(256) void k_prep(const float* __restrict__ x,
    const float* __restrict__ c1w, int* __restrict__ idxg,
    float* __restrict__ xyz, float* __restrict__ f0)
{
  __shared__ float4 pts4[1024];
  int tid = threadIdx.x;
  int b = blockIdx.x >> 8;
  int wid = tid >> 6, lane = tid & 63;
  for (int i = tid; i < 1024; i += 256) {
    float px = x[(b*3+0)*1024 + i];
    float py = x[(b*3+1)*1024 + i];
    float pz = x[(b*3+2)*1024 + i];
    pts4[i] = make_float4(px, py, pz, px*px + py*py + pz*pz);
  }
  __syncthreads();
  int nq = ((blockIdx.x & 255) << 2) + wid;
  float4 q = pts4[nq];
  int qrow = b*1024 + nq;
  {
    float w0 = c1w[lane*3+0], w1 = c1w[lane*3+1], w2 = c1w[lane*3+2];
    f0[(size_t)qrow*64 + lane] = q.x*w0 + q.y*w1 + q.z*w2;
  }
  unsigned int uk[16];
  #pragma unroll
  for (int i = 0; i < 16; ++i) {
    float4 pm = pts4[i*64 + lane];
    float d = 2.f*(q.x*pm.x + q.y*pm.y + q.z*pm.z) - q.w - pm.w;
    unsigned int bits = __float_as_uint(d);
    uk[i] = bits ^ ((bits & 0x80000000u) ? 0xFFFFFFFFu : 0x80000000u);
  }
  // binary search for 20th-largest key V
  unsigned int lo = 0u, hi = 0xFFFFFFFFu;
  while (lo < hi) {
    unsigned int mid = lo + ((hi - lo) >> 1);
    int cnt = 0;
    #pragma unroll
    for (int i = 0; i < 16; ++i) cnt += (uk[i] > mid) ? 1 : 0;
    cnt = wredi(cnt);
    if (cnt <= 19) hi = mid; else lo = mid + 1u;
  }
  unsigned int V = lo;
  unsigned int sel = 0; int cg = 0;
  #pragma unroll
  for (int i = 0; i < 16; ++i) if (uk[i] > V) { sel |= (1u << i); ++cg; }
  cg = wredi(cg);
  int r = 20 - cg;            // #equals to take, smallest index first (jax tie rule)
  unsigned int taken = 0;
  while (r > 0) {
    int jm = 0x7FFFFFFF;
    #pragma unroll
    for (int i = 0; i < 16; ++i)
      if ((uk[i] == V) && !((taken >> i) & 1u) && jm == 0x7FFFFFFF) jm = i*64 + lane;
    int jw = wmini(jm);
    if ((jw & 63) == lane) { int ii = jw >> 6; taken |= (1u << ii); sel |= (1u << ii); }
    --r;
  }
  int cl = __popc(sel);
  int pre = cl;
  #pragma unroll
  for (int o = 1; o < 64; o <<= 1) { int t = __shfl_up(pre, o, 64); if (lane >= o) pre += t; }
  int slot = pre - cl;
  #pragma unroll
  for (int i = 0; i < 16; ++i) {
    if ((sel >> i) & 1u) {
      int j = i*64 + lane;
      idxg[qrow*20 + slot] = b*1024 + j;
      float4 pm = pts4[j];
      float* xr = xyz + (size_t)(qrow*20 + slot)*6;
      xr[0] = pm.x - q.x; xr[1] = pm.y - q.y; xr[2] = pm.z - q.z;
      xr[3] = pm.x; xr[4] = pm.y; xr[5] = pm.z;
      ++slot;
    }
  }
}

// ---------------- repack conv5_w: m5[k][o] = w[o*128+k] ----------------
__global__ __launch_bounds__(256) void k_repack(const float* __restrict__ w, float* __restrict__ m5)
{
  int idx = blockIdx.x*256 + threadIdx.x;   // 131072
  int k = idx >> 10, o = idx & 1023;
  m5[idx] = w[o*128 + k];
}

// ---------------- stats: xyz moments (blocks 0..159) + bn1 partials (160..191) ----------------
__global__ __launch_bounds__(256) void k_stats(const float* __restrict__ xyz,
    const float* __restrict__ f0, float* __restrict__ hMom, float* __restrict__ b1P)
{
  __shared__ float lred[512];
  int tid = threadIdx.x, blk = blockIdx.x;
  int wid = tid >> 6, lane = tid & 63;
  if (blk < 160) {
    float m1[6] = {0,0,0,0,0,0};
    float m2[36];
    #pragma unroll
    for (int i = 0; i < 36; ++i) m2[i] = 0.f;
    for (int it = 0; it < 4; ++it) {
      size_t rr = (size_t)blk*1024 + it*256 + tid;
      const float* xr = xyz + rr*6;
      float v[6];
      #pragma unroll
      for (int d = 0; d < 6; ++d) v[d] = xr[d];
      #pragma unroll
      for (int d = 0; d < 6; ++d) {
        m1[d] += v[d];
        #pragma unroll
        for (int e = 0; e < 6; ++e) m2[d*6+e] += v[d]*v[e];
      }
    }
    #pragma unroll
    for (int i = 0; i < 6; ++i) m1[i] = wredf(m1[i]);
    #pragma unroll
    for (int i = 0; i < 36; ++i) m2[i] = wredf(m2[i]);
    if (lane == 0) {
      #pragma unroll
      for (int i = 0; i < 6; ++i) lred[wid*42 + i] = m1[i];
      #pragma unroll
      for (int i = 0; i < 36; ++i) lred[wid*42 + 6 + i] = m2[i];
    }
    __syncthreads();
    if (tid < 42) hMom[blk*42 + tid] = lred[tid] + lred[42+tid] + lred[84+tid] + lred[126+tid];
  } else {
    int pb = blk - 160;
    int c = tid & 63, rq = tid >> 6;
    float s = 0.f, qq = 0.f;
    for (int rr = 0; rr < 64; ++rr) {
      float v = f0[((size_t)(pb*256 + rq*64 + rr))*64 + c];
      s += v; qq += v*v;
    }
    lred[rq*128 + c*2] = s; lred[rq*128 + c*2 + 1] = qq;
    __syncthreads();
    if (tid < 128) b1P[pb*128 + tid] = lred[tid] + lred[128+tid] + lred[256+tid] + lred[384+tid];
  }
}

// ---------------- total moments (once) ----------------
__global__ __launch_bounds__(64) void k_mom(const float* __restrict__ hMom, float* __restrict__ mom42)
{
  int tid = threadIdx.x;
  if (tid < 42) {
    float s = 0.f;
    #pragma unroll 8
    for (int pb = 0; pb < 160; ++pb) s += hMom[pb*42 + tid];
    mom42[tid] = s / (float)KPn;
  }
}

// ---------------- per-stage coefficients (once per stage) ----------------
// coef[0..15]=sSc, [16..31]=sSh, [32..95]=pSc, [96..159]=pSh
__global__ __launch_bounds__(128) void k_coef(
    const float* __restrict__ mom42, const float* __restrict__ prevPart, int nPB,
    const float* __restrict__ w1, const float* __restrict__ sg, const float* __restrict__ sb,
    const float* __restrict__ bng, const float* __restrict__ bnb,
    float* __restrict__ coef)
{
  int tid = threadIdx.x;
  if (tid < 16) {
    float wv[6];
    #pragma unroll
    for (int d = 0; d < 6; ++d) wv[d] = w1[tid*6 + d];
    float mu = 0.f, E2 = 0.f;
    #pragma unroll
    for (int d = 0; d < 6; ++d) mu += wv[d]*mom42[d];
    #pragma unroll
    for (int d = 0; d < 6; ++d) {
      float qd = 0.f;
      #pragma unroll
      for (int e = 0; e < 6; ++e) qd += mom42[6 + d*6 + e]*wv[e];
      E2 += wv[d]*qd;
    }
    float var = E2 - mu*mu;
    float rst = rsqrtf(var + EPS_);
    float g = sg[tid];
    coef[tid] = g*rst;
    coef[16 + tid] = sb[tid] - mu*g*rst;
  } else if (tid >= 64) {
    int c = tid - 64;
    float s = 0.f, qq = 0.f;
    #pragma unroll 8
    for (int p = 0; p < nPB; ++p) { s += prevPart[(p*64 + c)*2]; qq += prevPart[(p*64 + c)*2 + 1]; }
    float mu = s / 8192.f;
    float var = qq / 8192.f - mu*mu;
    float rst = rsqrtf(var + EPS_);
    float g = bng[c];
    coef[32 + c] = g*rst;
    coef[96 + c] = bnb[c] - mu*g*rst;
  }
}

// ---------------- bn4 scale/shift (once) ----------------
__global__ __launch_bounds__(128) void k_bnc(const float* __restrict__ part,
    const float* __restrict__ g, const float* __restrict__ b, float* __restrict__ out)
{
  int c = threadIdx.x;   // 128
  float s = 0.f, qq = 0.f;
  #pragma unroll 8
  for (int p = 0; p < 128; ++p) { s += part[(p*128 + c)*2]; qq += part[(p*128 + c)*2 + 1]; }
  float mu = s / 8192.f;
  float var = qq / 8192.f - mu*mu;
  float rst = rsqrtf(var + EPS_);
  out[c] = g[c]*rst;
  out[128 + c] = b[c] - mu*g[c]*rst;
}

// ---------------- W-build: scorenet + gather(prev feat w/ bn+relu) ----------------
__global__ __launch_bounds__(256) void k_wbuild(
    const float* __restrict__ xyz, const int* __restrict__ idxg,
    const float* __restrict__ aprev, const float* __restrict__ coef,
    const float* __restrict__ w1, const float* __restrict__ w2, const float* __restrict__ b2,
    float* __restrict__ Wo)
{
  __shared__ float coefS[160];
  __shared__ float scoreS[4][20][8];
  int tid = threadIdx.x;
  if (tid < 160) coefS[tid] = coef[tid];
  __syncthreads();
  if (tid < 80) {
    int pl = tid / 20, k2 = tid % 20;
    int p = blockIdx.x*4 + pl;
    const float* xr = xyz + (size_t)(p*20 + k2)*6;
    float v0=xr[0],v1=xr[1],v2=xr[2],v3=xr[3],v4=xr[4],v5=xr[5];
    float hb[16];
    #pragma unroll
    for (int c = 0; c < 16; ++c) {
      float h = v0*w1[c*6+0]+v1*w1[c*6+1]+v2*w1[c*6+2]+v3*w1[c*6+3]+v4*w1[c*6+4]+v5*w1[c*6+5];
      hb[c] = fmaxf(0.f, h*coefS[c] + coefS[16+c]);
    }
    float lg[8]; float mx = -3.4e38f;
    #pragma unroll
    for (int m = 0; m < 8; ++m) {
      float s = b2[m];
      #pragma unroll
      for (int c = 0; c < 16; ++c) s += hb[c]*w2[m*16+c];
      lg[m] = s; mx = fmaxf(mx, s);
    }
    float den = 0.f;
    #pragma unroll
    for (int m = 0; m < 8; ++m) { lg[m] = expf(lg[m]-mx); den += lg[m]; }
    #pragma unroll
    for (int m = 0; m < 8; ++m) scoreS[pl][k2][m] = lg[m]/den;
  }
  __syncthreads();
  int wid = tid >> 6, lane = tid & 63;
  int p = blockIdx.x*4 + wid;
  float ps = coefS[32 + lane], ph = coefS[96 + lane];
  float acc[8];
  #pragma unroll
  for (int m = 0; m < 8; ++m) acc[m] = 0.f;
  const int* ip = idxg + p*20;
  #pragma unroll
  for (int k = 0; k < 20; ++k) {
    int j = ip[k];
    float v = aprev[(size_t)j*64 + lane];
    v = fmaxf(0.f, v*ps + ph);
    #pragma unroll
    for (int m = 0; m < 8; ++m) acc[m] += scoreS[wid][k][m]*v;
  }
  #pragma unroll
  for (int m = 0; m < 8; ++m) Wo[(size_t)p*512 + m*64 + lane] = acc[m];
}

// ---------------- generic tiled GEMM (64 rows x CT cols per block) ----------------
template<int KD, int CO, int CT, int BMODE, bool BNA, bool DOMAX, bool WRITEC>
__global__ __launch_bounds__(256) void k_gemm(
    const float* __restrict__ A, const float* __restrict__ Bsrc, float* __restrict__ C,
    const float* __restrict__ bnSc, const float* __restrict__ bnSh,
    float* __restrict__ outPart, float* __restrict__ outMax)
{
  constexpr int TJ = CT/16;
  __shared__ __align__(16) float As[64*64];
  __shared__ __align__(16) float Bs[64*CT];
  __shared__ float aSc[128], aSh[128];
  int tid = threadIdx.x;
  int rb = blockIdx.x, gy = blockIdx.y;
  if constexpr (BNA) {
    if (tid < KD) { aSc[tid] = bnSc[tid]; aSh[tid] = bnSh[tid]; }
    __syncthreads();
  }
  float acc[4][TJ];
  #pragma unroll
  for (int i = 0; i < 4; ++i)
    #pragma unroll
    for (int j = 0; j < TJ; ++j) acc[i][j] = 0.f;
  int pg = tid >> 4, cgi = tid & 15;
  for (int kc = 0; kc < KD/64; ++kc) {
    {
      int row = tid >> 2, kq = tid & 3;
      const float* ap = A + (size_t)(rb*64 + row)*KD + kc*64 + kq*16;
      #pragma unroll
      for (int u = 0; u < 4; ++u) {
        float4 v = *(const float4*)(ap + u*4);
        int k0 = kq*16 + u*4;
        if constexpr (BNA) {
          int kb = kc*64 + k0;
          v.x = fmaxf(0.f, v.x*aSc[kb+0] + aSh[kb+0]);
          v.y = fmaxf(0.f, v.y*aSc[kb+1] + aSh[kb+1]);
          v.z = fmaxf(0.f, v.z*aSc[kb+2] + aSh[kb+2]);
          v.w = fmaxf(0.f, v.w*aSc[kb+3] + aSh[kb+3]);
        }
        As[(k0+0)*64 + row] = v.x;
        As[(k0+1)*64 + row] = v.y;
        As[(k0+2)*64 + row] = v.z;
        As[(k0+3)*64 + row] = v.w;
      }
    }
    {
      #pragma unroll
      for (int pass = 0; pass < CT/16; ++pass) {
        int f = pass*256 + tid;
        int kk = f / (CT/4);
        int oo = (f % (CT/4))*4;
        const float* bp;
        if constexpr (BMODE == 0) bp = Bsrc + (size_t)kk*(8*CO) + kc*CO + gy*CT + oo;
        else                      bp = Bsrc + (size_t)(kc*64 + kk)*CO + gy*CT + oo;
        *(float4*)(Bs + kk*CT + oo) = *(const float4*)bp;
      }
    }
    __syncthreads();
    #pragma unroll 4
    for (int kk = 0; kk < 64; ++kk) {
      float4 av = *(const float4*)(As + kk*64 + pg*4);
      #pragma unroll
      for (int j4 = 0; j4 < TJ/4; ++j4) {
        float4 bv = *(const float4*)(Bs + kk*CT + cgi*TJ + j4*4);
        acc[0][j4*4+0] += av.x*bv.x; acc[0][j4*4+1] += av.x*bv.y; acc[0][j4*4+2] += av.x*bv.z; acc[0][j4*4+3] += av.x*bv.w;
        acc[1][j4*4+0] += av.y*bv.x; acc[1][j4*4+1] += av.y*bv.y; acc[1][j4*4+2] += av.y*bv.z; acc[1][j4*4+3] += av.y*bv.w;
        acc[2][j4*4+0] += av.z*bv.x; acc[2][j4*4+1] += av.z*bv.y; acc[2][j4*4+2] += av.z*bv.z; acc[2][j4*4+3] += av.z*bv.w;
        acc[3][j4*4+0] += av.w*bv.x; acc[3][j4*4+1] += av.w*bv.y; acc[3][j4*4+2] += av.w*bv.z; acc[3][j4*4+3] += av.w*bv.w;
      }
    }
    __syncthreads();
  }
  if constexpr (WRITEC) {
    #pragma unroll
    for (int i = 0; i < 4; ++i) {
      size_t row = (size_t)rb*64 + pg*4 + i;
      #pragma unroll
      for (int j4 = 0; j4 < TJ/4; ++j4) {
        float4 v;
        v.x = acc[i][j4*4+0]; v.y = acc[i][j4*4+1]; v.z = acc[i][j4*4+2]; v.w = acc[i][j4*4+3];
        *(float4*)(C + row*CO + gy*CT + cgi*TJ + j4*4) = v;
      }
    }
  }
  float* red = As;   // As no longer needed
  #pragma unroll
  for (int j = 0; j < TJ; ++j)
    red[pg*CT + cgi*TJ + j] = acc[0][j]+acc[1][j]+acc[2][j]+acc[3][j];
  __syncthreads();
  if (tid < CT) {
    float t = 0.f;
    for (int p2 = 0; p2 < 16; ++p2) t += red[p2*CT + tid];
    outPart[((size_t)rb*CO + gy*CT + tid)*2] = t;
  }
  __syncthreads();
  #pragma unroll
  for (int j = 0; j < TJ; ++j)
    red[pg*CT + cgi*TJ + j] = acc[0][j]*acc[0][j]+acc[1][j]*acc[1][j]+acc[2][j]*acc[2][j]+acc[3][j]*acc[3][j];
  __syncthreads();
  if (tid < CT) {
    float t = 0.f;
    for (int p2 = 0; p2 < 16; ++p2) t += red[p2*CT + tid];
    outPart[((size_t)rb*CO + gy*CT + tid)*2 + 1] = t;
  }
  if constexpr (DOMAX) {
    __syncthreads();
    #pragma unroll
    for (int j = 0; j < TJ; ++j)
      red[pg*CT + cgi*TJ + j] = fmaxf(fmaxf(acc[0][j],acc[1][j]), fmaxf(acc[2][j],acc[3][j]));
    __syncthreads();
    if (tid < CT) {
      float t = -3.4e38f;
      for (int p2 = 0; p2 < 16; ++p2) t = fmaxf(t, red[p2*CT + tid]);
      outMax[(size_t)rb*CO + gy*CT + tid] = t;
    }
  }
}

// ---------------- bn5 + relu + maxpool over n ----------------
__global__ __launch_bounds__(256) void k_pool(const float* __restrict__ p5, const float* __restrict__ mx5,
    const float* __restrict__ g5, const float* __restrict__ b5, float* __restrict__ pool)
{
  int gid = blockIdx.x*256 + threadIdx.x;   // 8192
  int b = gid >> 10, ch = gid & 1023;
  float s = 0.f, qq = 0.f;
  for (int rb = 0; rb < 128; ++rb) {
    s  += p5[((size_t)rb*1024 + ch)*2];
    qq += p5[((size_t)rb*1024 + ch)*2 + 1];
  }
  float mu = s / 8192.f;
  float var = qq / 8192.f - mu*mu;
  float rst = rsqrtf(var + EPS_);
  float mx = -3.4e38f;
  for (int t = 0; t < 16; ++t) mx = fmaxf(mx, mx5[(size_t)(b*16 + t)*1024 + ch]);
  pool[gid] = fmaxf(0.f, g5[ch]*(mx - mu)*rst + b5[ch]);
}

// ---------------- lin1 ----------------
__global__ __launch_bounds__(256) void k_lin1(const float* __restrict__ pool,
    const float* __restrict__ w, float* __restrict__ a6)
{
  int idx = blockIdx.x*256 + threadIdx.x;   // 4096 = 8*512
  int r = idx >> 9, c = idx & 511;
  const float4* pr = (const float4*)(pool + r*1024);
  const float4* wr = (const float4*)(w + (size_t)c*1024);
  float s = 0.f;
  for (int t = 0; t < 256; ++t) {
    float4 a = pr[t], bb = wr[t];
    s += a.x*bb.x + a.y*bb.y + a.z*bb.z + a.w*bb.w;
  }
  a6[idx] = s;
}

// ---------------- bn6 + relu + lin2 + bias ----------------
__global__ __launch_bounds__(256) void k_head(const float* __restrict__ a6,
    const float* __restrict__ g6, const float* __restrict__ b6,
    const float* __restrict__ w2, const float* __restrict__ bb,
    float* __restrict__ out)
{
  __shared__ float f6[8*512];
  int tid = threadIdx.x;
  for (int c = tid; c < 512; c += 256) {
    float v[8]; float s = 0.f;
    #pragma unroll
    for (int r = 0; r < 8; ++r) { v[r] = a6[r*512 + c]; s += v[r]; }
    float mu = s / 8.f;
    float qq = 0.f;
    #pragma unroll
    for (int r = 0; r < 8; ++r) { float d = v[r] - mu; qq += d*d; }
    float var = qq / 8.f;
    float rst = rsqrtf(var + EPS_);
    float sc = g6[c]*rst, sh = b6[c] - mu*g6[c]*rst;
    #pragma unroll
    for (int r = 0; r < 8; ++r) f6[r*512 + c] = fmaxf(0.f, v[r]*sc + sh);
  }
  __syncthreads();
  for (int o = tid; o < 320; o += 256) {
    int r = o / 40, c2 = o % 40;
    float s = bb[c2];
    for (int k = 0; k < 512; ++k) s += f6[r*512 + k]*w2[c2*512 + k];
    out[o] = s;
  }
}

extern "C" void kernel_launch(void* const* d_in, const int* in_sizes, int n_in,
                              void* d_out, int out_size, void* d_ws, size_t ws_size,
                              hipStream_t stream) {
  (void)in_sizes; (void)n_in; (void)out_size; (void)ws_size;
  const float* x     = (const float*)d_in[0];
  const float* c1w   = (const float*)d_in[1];
  const float* bn1g  = (const float*)d_in[2];
  const float* bn1b  = (const float*)d_in[3];
  const float* mat2  = (const float*)d_in[4];
  const float* mat3  = (const float*)d_in[5];
  const float* mat4  = (const float*)d_in[6];
  const float* sn2w1 = (const float*)d_in[7];
  const float* sn2g  = (const float*)d_in[8];
  const float* sn2b  = (const float*)d_in[9];
  const float* sn2w2 = (const float*)d_in[10];
  const float* sn2b2 = (const float*)d_in[11];
  const float* sn3w1 = (const float*)d_in[12];
  const float* sn3g  = (const float*)d_in[13];
  const float* sn3b  = (const float*)d_in[14];
  const float* sn3w2 = (const float*)d_in[15];
  const float* sn3b2 = (const float*)d_in[16];
  const float* sn4w1 = (const float*)d_in[17];
  const float* sn4g  = (const float*)d_in[18];
  const float* sn4b  = (const float*)d_in[19];
  const float* sn4w2 = (const float*)d_in[20];
  const float* sn4b2 = (const float*)d_in[21];
  const float* bn2g  = (const float*)d_in[22];
  const float* bn2b  = (const float*)d_in[23];
  const float* bn3g  = (const float*)d_in[24];
  const float* bn3b  = (const float*)d_in[25];
  const float* bn4g  = (const float*)d_in[26];
  const float* bn4b  = (const float*)d_in[27];
  const float* c5w   = (const float*)d_in[28];
  const float* bn5g  = (const float*)d_in[29];
  const float* bn5b  = (const float*)d_in[30];
  const float* l1w   = (const float*)d_in[31];
  const float* bn6g  = (const float*)d_in[32];
  const float* bn6b  = (const float*)d_in[33];
  const float* l2w   = (const float*)d_in[34];
  const float* l2b   = (const float*)d_in[35];
  float* ws   = (float*)d_ws;
  float* f0   = ws + OFF_F0;
  int*   idxg = (int*)(ws + OFF_IDX);
  float* xyz  = ws + OFF_XYZ;
  float* hMom = ws + OFF_HM;
  float* b1P  = ws + OFF_B1P;
  float* mom42= ws + OFF_MOM;
  float* coef = ws + OFF_COEF;
  float* bn4c = ws + OFF_BN4C;
  float* W    = ws + OFF_W;
  float* a2   = ws + OFF_A2;
  float* a3   = ws + OFF_A3;
  float* a4   = ws + OFF_A4;
  float* p2   = ws + OFF_P2;
  float* p3   = ws + OFF_P3;
  float* p4   = ws + OFF_P4;
  float* p5   = ws + OFF_P5;
  float* mx5  = ws + OFF_MX5;
  float* m5   = ws + OFF_M5;
  float* pool = ws + OFF_POOL;
  float* a6   = ws + OFF_A6;
  float* out  = (float*)d_out;

  k_prep<<<2048, 256, 0, stream>>>(x, c1w, idxg, xyz, f0);
  k_repack<<<512, 256, 0, stream>>>(c5w, m5);
  k_stats<<<192, 256, 0, stream>>>(xyz, f0, hMom, b1P);
  k_mom<<<1, 64, 0, stream>>>(hMom, mom42);

  k_coef<<<1, 128, 0, stream>>>(mom42, b1P, 32, sn2w1, sn2g, sn2b, bn1g, bn1b, coef);
  k_wbuild<<<2048, 256, 0, stream>>>(xyz, idxg, f0, coef, sn2w1, sn2w2, sn2b2, W);
  k_gemm<512,64,64,0,false,false,true><<<dim3(128,1), 256, 0, stream>>>(
      W, mat2, a2, nullptr, nullptr, p2, nullptr);

  k_coef<<<1, 128, 0, stream>>>(mom42, p2, 128, sn3w1, sn3g, sn3b, bn2g, bn2b, coef);
  k_wbuild<<<2048, 256, 0, stream>>>(xyz, idxg, a2, coef, sn3w1, sn3w2, sn3b2, W);
  k_gemm<512,64,64,0,false,false,true><<<dim3(128,1), 256, 0, stream>>>(
      W, mat3, a3, nullptr, nullptr, p3, nullptr);

  k_coef<<<1, 128, 0, stream>>>(mom42, p3, 128, sn4w1, sn4g, sn4b, bn3g, bn3b, coef);
  k_wbuild<<<2048, 256, 0, stream>>>(xyz, idxg, a3, coef, sn4w1, sn4w2, sn4b2, W);
  k_gemm<512,128,128,0,false,false,true><<<dim3(128,1), 256, 0, stream>>>(
      W, mat4, a4, nullptr, nullptr, p4, nullptr);

  k_bnc<<<1, 128, 0, stream>>>(p4, bn4g, bn4b, bn4c);
  k_gemm<128,1024,128,1,true,true,false><<<dim3(128,8), 256, 0, stream>>>(
      a4, m5, nullptr, bn4c, bn4c + 128, p5, mx5);

  k_pool<<<32, 256, 0, stream>>>(p5, mx5, bn5g, bn5b, pool);
  k_lin1<<<16, 256, 0, stream>>>(pool, l1w, a6);
  k_head<<<1, 256, 0, stream>>>(a6, bn6g, bn6b, l2w, l2b, out);
}

// Round 3
// 206.909 us; speedup vs baseline: 2.0087x; 1.4492x over previous
//
#include <hip/hip_runtime.h>

#define PPn 8192
#define KKn 20
#define KPn (PPn*KKn)
constexpr float EPS_ = 1e-5f;

typedef __attribute__((ext_vector_type(8))) short s8v;
typedef __attribute__((ext_vector_type(4))) float f32x4;
#define MFMA16 __builtin_amdgcn_mfma_f32_16x16x32_bf16

// ---- ws layout (float offsets) ----
constexpr size_t OFF_F0   = 0;              // 8192*64 f32
constexpr size_t OFF_IDX  = 524288;         // 8192*20 int
constexpr size_t OFF_XYZ  = 688128;         // 8192*20*6 f32
constexpr size_t OFF_HM   = 1671168;        // 160*42
constexpr size_t OFF_B1P  = 1677888;        // 32*64*2
constexpr size_t OFF_MOM  = 1681984;        // 42 pad 64
constexpr size_t OFF_COEF = 1682048;        // 160 pad 192
constexpr size_t OFF_BN4C = 1682240;        // 256
constexpr size_t OFF_W2   = 1682496;        // 8192*1024 bf16 = 4194304 f
constexpr size_t OFF_A2   = 5876800;        // 8192*64 f32 (a3 aliases this)
constexpr size_t OFF_A4   = 6401088;        // 8192*128 f32
constexpr size_t OFF_P2   = 7449664;        // 128*64*2
constexpr size_t OFF_P3   = 7466048;        // 128*64*2
constexpr size_t OFF_P4   = 7482432;        // 128*128*2
constexpr size_t OFF_P5   = 7515200;        // 128*1024*2
constexpr size_t OFF_MX5  = 7777344;        // 128*1024
constexpr size_t OFF_BT2  = 7908416;        // 64*1536 bf16 = 49152 f
constexpr size_t OFF_BT3  = 7957568;        // 64*1536 bf16
constexpr size_t OFF_BT4  = 8006720;        // 128*1536 bf16 = 98304 f
constexpr size_t OFF_BT5  = 8105024;        // 1024*384 bf16 = 196608 f
constexpr size_t OFF_POOL = 8301632;        // 8*1024
constexpr size_t OFF_A6   = 8309824;        // 8*512
// total 8313920 floats = 33.3 MB (< round-1's 34.3 MB, known to fit)

__device__ __forceinline__ float wredf(float v) {
  #pragma unroll
  for (int o = 32; o > 0; o >>= 1) v += __shfl_xor(v, o, 64);
  return v;
}
__device__ __forceinline__ int wredi(int v) {
  #pragma unroll
  for (int o = 32; o > 0; o >>= 1) v += __shfl_xor(v, o, 64);
  return v;
}
__device__ __forceinline__ int wmini(int v) {
  #pragma unroll
  for (int o = 32; o > 0; o >>= 1) v = min(v, __shfl_xor(v, o, 64));
  return v;
}
__device__ __forceinline__ unsigned short f2bf(float f) {   // RNE
  unsigned int u = __float_as_uint(f);
  return (unsigned short)((u + 0x7FFFu + ((u >> 16) & 1u)) >> 16);
}
__device__ __forceinline__ float bf2f(unsigned short h) {
  return __uint_as_float(((unsigned int)h) << 16);
}

// ---------------- KNN + xyz + f0pre ----------------
__global__ __launch_bounds__(256) void k_prep(const float* __restrict__ x,
    const float* __restrict__ c1w, int* __restrict__ idxg,
    float* __restrict__ xyz, float* __restrict__ f0)
{
  __shared__ float4 pts4[1024];
  int tid = threadIdx.x;
  int b = blockIdx.x >> 8;
  int wid = tid >> 6, lane = tid & 63;
  for (int i = tid; i < 1024; i += 256) {
    float px = x[(b*3+0)*1024 + i];
    float py = x[(b*3+1)*1024 + i];
    float pz = x[(b*3+2)*1024 + i];
    pts4[i] = make_float4(px, py, pz, px*px + py*py + pz*pz);
  }
  __syncthreads();
  int nq = ((blockIdx.x & 255) << 2) + wid;
  float4 q = pts4[nq];
  int qrow = b*1024 + nq;
  {
    float w0 = c1w[lane*3+0], w1 = c1w[lane*3+1], w2 = c1w[lane*3+2];
    f0[(size_t)qrow*64 + lane] = q.x*w0 + q.y*w1 + q.z*w2;
  }
  unsigned int uk[16];
  #pragma unroll
  for (int i = 0; i < 16; ++i) {
    float4 pm = pts4[i*64 + lane];
    float d = 2.f*(q.x*pm.x + q.y*pm.y + q.z*pm.z) - q.w - pm.w;
    unsigned int bits = __float_as_uint(d);
    uk[i] = bits ^ ((bits & 0x80000000u) ? 0xFFFFFFFFu : 0x80000000u);
  }
  unsigned int lo = 0u, hi = 0xFFFFFFFFu;
  while (lo < hi) {
    unsigned int mid = lo + ((hi - lo) >> 1);
    int cnt = 0;
    #pragma unroll
    for (int i = 0; i < 16; ++i) cnt += (uk[i] > mid) ? 1 : 0;
    cnt = wredi(cnt);
    if (cnt <= 19) hi = mid; else lo = mid + 1u;
  }
  unsigned int V = lo;
  unsigned int sel = 0; int cg = 0;
  #pragma unroll
  for (int i = 0; i < 16; ++i) if (uk[i] > V) { sel |= (1u << i); ++cg; }
  cg = wredi(cg);
  int r = 20 - cg;
  unsigned int taken = 0;
  while (r > 0) {
    int jm = 0x7FFFFFFF;
    #pragma unroll
    for (int i = 0; i < 16; ++i)
      if ((uk[i] == V) && !((taken >> i) & 1u) && jm == 0x7FFFFFFF) jm = i*64 + lane;
    int jw = wmini(jm);
    if ((jw & 63) == lane) { int ii = jw >> 6; taken |= (1u << ii); sel |= (1u << ii); }
    --r;
  }
  int cl = __popc(sel);
  int pre = cl;
  #pragma unroll
  for (int o = 1; o < 64; o <<= 1) { int t = __shfl_up(pre, o, 64); if (lane >= o) pre += t; }
  int slot = pre - cl;
  #pragma unroll
  for (int i = 0; i < 16; ++i) {
    if ((sel >> i) & 1u) {
      int j = i*64 + lane;
      idxg[qrow*20 + slot] = b*1024 + j;
      float4 pm = pts4[j];
      float* xr = xyz + (size_t)(qrow*20 + slot)*6;
      xr[0] = pm.x - q.x; xr[1] = pm.y - q.y; xr[2] = pm.z - q.z;
      xr[3] = pm.x; xr[4] = pm.y; xr[5] = pm.z;
      ++slot;
    }
  }
}

// ---------------- B-split prep: Bt[o][k'] bf16, panels [Bh;Bh;Bl] ----------------
__global__ __launch_bounds__(256) void k_bsplit(
    const float* __restrict__ mat2, const float* __restrict__ mat3,
    const float* __restrict__ mat4, const float* __restrict__ c5w,
    unsigned short* __restrict__ bt2, unsigned short* __restrict__ bt3,
    unsigned short* __restrict__ bt4, unsigned short* __restrict__ bt5)
{
  int blk = blockIdx.x, tid = threadIdx.x;
  float f; unsigned short* dst; int e;
  if (blk < 384) {                 // Bt2: 64 x 1536
    e = blk*256 + tid;
    int o = e / 1536, k2 = e % 1536, p = k2 >> 9, k = k2 & 511;
    f = mat2[(k & 63)*512 + (k >> 6)*64 + o];
    unsigned short h = f2bf(f);
    bt2[e] = (p < 2) ? h : f2bf(f - bf2f(h));
  } else if (blk < 768) {          // Bt3
    e = (blk - 384)*256 + tid;
    int o = e / 1536, k2 = e % 1536, p = k2 >> 9, k = k2 & 511;
    f = mat3[(k & 63)*512 + (k >> 6)*64 + o];
    unsigned short h = f2bf(f);
    bt3[e] = (p < 2) ? h : f2bf(f - bf2f(h));
  } else if (blk < 1536) {         // Bt4: 128 x 1536
    e = (blk - 768)*256 + tid;
    int o = e / 1536, k2 = e % 1536, p = k2 >> 9, k = k2 & 511;
    f = mat4[(k & 63)*1024 + (k >> 6)*128 + o];
    unsigned short h = f2bf(f);
    bt4[e] = (p < 2) ? h : f2bf(f - bf2f(h));
  } else {                         // Bt5: 1024 x 384
    e = (blk - 1536)*256 + tid;
    int o = e / 384, k2 = e % 384, p = k2 >> 7, k = k2 & 127;
    f = c5w[o*128 + k];
    unsigned short h = f2bf(f);
    bt5[e] = (p < 2) ? h : f2bf(f - bf2f(h));
  }
}

// ---------------- stats: xyz moments + bn1 partials ----------------
__global__ __launch_bounds__(256) void k_stats(const float* __restrict__ xyz,
    const float* __restrict__ f0, float* __restrict__ hMom, float* __restrict__ b1P)
{
  __shared__ float lred[512];
  int tid = threadIdx.x, blk = blockIdx.x;
  int wid = tid >> 6, lane = tid & 63;
  if (blk < 160) {
    float m1[6] = {0,0,0,0,0,0};
    float m2[36];
    #pragma unroll
    for (int i = 0; i < 36; ++i) m2[i] = 0.f;
    for (int it = 0; it < 4; ++it) {
      size_t rr = (size_t)blk*1024 + it*256 + tid;
      const float* xr = xyz + rr*6;
      float v[6];
      #pragma unroll
      for (int d = 0; d < 6; ++d) v[d] = xr[d];
      #pragma unroll
      for (int d = 0; d < 6; ++d) {
        m1[d] += v[d];
        #pragma unroll
        for (int e = 0; e < 6; ++e) m2[d*6+e] += v[d]*v[e];
      }
    }
    #pragma unroll
    for (int i = 0; i < 6; ++i) m1[i] = wredf(m1[i]);
    #pragma unroll
    for (int i = 0; i < 36; ++i) m2[i] = wredf(m2[i]);
    if (lane == 0) {
      #pragma unroll
      for (int i = 0; i < 6; ++i) lred[wid*42 + i] = m1[i];
      #pragma unroll
      for (int i = 0; i < 36; ++i) lred[wid*42 + 6 + i] = m2[i];
    }
    __syncthreads();
    if (tid < 42) hMom[blk*42 + tid] = lred[tid] + lred[42+tid] + lred[84+tid] + lred[126+tid];
  } else {
    int pb = blk - 160;
    int c = tid & 63, rq = tid >> 6;
    float s = 0.f, qq = 0.f;
    for (int rr = 0; rr < 64; ++rr) {
      float v = f0[((size_t)(pb*256 + rq*64 + rr))*64 + c];
      s += v; qq += v*v;
    }
    lred[rq*128 + c*2] = s; lred[rq*128 + c*2 + 1] = qq;
    __syncthreads();
    if (tid < 128) b1P[pb*128 + tid] = lred[tid] + lred[128+tid] + lred[256+tid] + lred[384+tid];
  }
}

// ---------------- total moments (once) ----------------
__global__ __launch_bounds__(64) void k_mom(const float* __restrict__ hMom, float* __restrict__ mom42)
{
  int tid = threadIdx.x;
  if (tid < 42) {
    float s = 0.f;
    #pragma unroll 8
    for (int pb = 0; pb < 160; ++pb) s += hMom[pb*42 + tid];
    mom42[tid] = s / (float)KPn;
  }
}

// ---------------- per-stage coefficients ----------------
__global__ __launch_bounds__(128) void k_coef(
    const float* __restrict__ mom42, const float* __restrict__ prevPart, int nPB,
    const float* __restrict__ w1, const float* __restrict__ sg, const float* __restrict__ sb,
    const float* __restrict__ bng, const float* __restrict__ bnb,
    float* __restrict__ coef)
{
  int tid = threadIdx.x;
  if (tid < 16) {
    float wv[6];
    #pragma unroll
    for (int d = 0; d < 6; ++d) wv[d] = w1[tid*6 + d];
    float mu = 0.f, E2 = 0.f;
    #pragma unroll
    for (int d = 0; d < 6; ++d) mu += wv[d]*mom42[d];
    #pragma unroll
    for (int d = 0; d < 6; ++d) {
      float qd = 0.f;
      #pragma unroll
      for (int e = 0; e < 6; ++e) qd += mom42[6 + d*6 + e]*wv[e];
      E2 += wv[d]*qd;
    }
    float var = E2 - mu*mu;
    float rst = rsqrtf(var + EPS_);
    float g = sg[tid];
    coef[tid] = g*rst;
    coef[16 + tid] = sb[tid] - mu*g*rst;
  } else if (tid >= 64) {
    int c = tid - 64;
    float s = 0.f, qq = 0.f;
    #pragma unroll 8
    for (int p = 0; p < nPB; ++p) { s += prevPart[(p*64 + c)*2]; qq += prevPart[(p*64 + c)*2 + 1]; }
    float mu = s / 8192.f;
    float var = qq / 8192.f - mu*mu;
    float rst = rsqrtf(var + EPS_);
    float g = bng[c];
    coef[32 + c] = g*rst;
    coef[96 + c] = bnb[c] - mu*g*rst;
  }
}

// ---------------- bn4 scale/shift (once) ----------------
__global__ __launch_bounds__(128) void k_bnc(const float* __restrict__ part,
    const float* __restrict__ g, const float* __restrict__ b, float* __restrict__ out)
{
  int c = threadIdx.x;
  float s = 0.f, qq = 0.f;
  #pragma unroll 8
  for (int p = 0; p < 128; ++p) { s += part[(p*128 + c)*2]; qq += part[(p*128 + c)*2 + 1]; }
  float mu = s / 8192.f;
  float var = qq / 8192.f - mu*mu;
  float rst = rsqrtf(var + EPS_);
  out[c] = g[c]*rst;
  out[128 + c] = b[c] - mu*g[c]*rst;
}

// ---------------- W-build: scorenet + gather, emits hi/lo bf16 panels ----------------
__global__ __launch_bounds__(256) void k_wbuild(
    const float* __restrict__ xyz, const int* __restrict__ idxg,
    const float* __restrict__ aprev, const float* __restrict__ coef,
    const float* __restrict__ w1, const float* __restrict__ w2, const float* __restrict__ b2,
    unsigned short* __restrict__ Wo)
{
  __shared__ float coefS[160];
  __shared__ float scoreS[4][20][8];
  int tid = threadIdx.x;
  if (tid < 160) coefS[tid] = coef[tid];
  __syncthreads();
  if (tid < 80) {
    int pl = tid / 20, k2 = tid % 20;
    int p = blockIdx.x*4 + pl;
    const float* xr = xyz + (size_t)(p*20 + k2)*6;
    float v0=xr[0],v1=xr[1],v2=xr[2],v3=xr[3],v4=xr[4],v5=xr[5];
    float hb[16];
    #pragma unroll
    for (int c = 0; c < 16; ++c) {
      float h = v0*w1[c*6+0]+v1*w1[c*6+1]+v2*w1[c*6+2]+v3*w1[c*6+3]+v4*w1[c*6+4]+v5*w1[c*6+5];
      hb[c] = fmaxf(0.f, h*coefS[c] + coefS[16+c]);
    }
    float lg[8]; float mx = -3.4e38f;
    #pragma unroll
    for (int m = 0; m < 8; ++m) {
      float s = b2[m];
      #pragma unroll
      for (int c = 0; c < 16; ++c) s += hb[c]*w2[m*16+c];
      lg[m] = s; mx = fmaxf(mx, s);
    }
    float den = 0.f;
    #pragma unroll
    for (int m = 0; m < 8; ++m) { lg[m] = expf(lg[m]-mx); den += lg[m]; }
    #pragma unroll
    for (int m = 0; m < 8; ++m) scoreS[pl][k2][m] = lg[m]/den;
  }
  __syncthreads();
  int wid = tid >> 6, lane = tid & 63;
  int p = blockIdx.x*4 + wid;
  float ps = coefS[32 + lane], ph = coefS[96 + lane];
  float acc[8];
  #pragma unroll
  for (int m = 0; m < 8; ++m) acc[m] = 0.f;
  const int* ip = idxg + p*20;
  #pragma unroll
  for (int k = 0; k < 20; ++k) {
    int j = ip[k];
    float v = aprev[(size_t)j*64 + lane];
    v = fmaxf(0.f, v*ps + ph);
    #pragma unroll
    for (int m = 0; m < 8; ++m) acc[m] += scoreS[wid][k][m]*v;
  }
  #pragma unroll
  for (int m = 0; m < 8; ++m) {
    float v = acc[m];
    unsigned short h = f2bf(v);
    unsigned short l = f2bf(v - bf2f(h));
    Wo[(size_t)p*1024 + m*64 + lane] = h;
    Wo[(size_t)p*1024 + 512 + m*64 + lane] = l;
  }
}

// ---------------- MFMA gemm: C[8192xCO] = W'(bf16 3-panel) x Bt ----------------
// block: 64 rows x 64 cols, 4 waves (2x2 of 32x32), K'=1536 in 24 iters of 64
template<int CO>
__global__ __launch_bounds__(256) void k_mg(const unsigned short* __restrict__ W2,
    const unsigned short* __restrict__ Bt, float* __restrict__ C,
    float* __restrict__ outPart)
{
  __shared__ __align__(16) unsigned short As[4096];
  __shared__ __align__(16) unsigned short Bs[4096];
  __shared__ float colS[4][64], colQ[4][64];
  int tid = threadIdx.x;
  int rb = blockIdx.x, gy = blockIdx.y;
  int w = tid >> 6, lane = tid & 63;
  int wr = w & 1, wc = w >> 1;
  int r = tid >> 2, q = tid & 3;
  f32x4 acc00 = {0,0,0,0}, acc01 = {0,0,0,0}, acc10 = {0,0,0,0}, acc11 = {0,0,0,0};
  const size_t arow = (size_t)(rb*64 + r)*1024;
  const size_t brow = (size_t)(gy*64 + r)*1536;
  float4 ra0, ra1, rbv0, rbv1;
  #define MG_LOAD(IT) { int p_ = (IT) >> 3, kk_ = ((IT) & 7) << 6; \
    const float4* ap_ = (const float4*)(W2 + arow + (p_ == 1 ? 512 : 0) + kk_ + q*16); \
    ra0 = ap_[0]; ra1 = ap_[1]; \
    const float4* bp_ = (const float4*)(Bt + brow + (size_t)(IT)*64 + q*16); \
    rbv0 = bp_[0]; rbv1 = bp_[1]; }
  MG_LOAD(0);
  int wbase = r*128 + q*32, sw = (r & 7) << 4;
  for (int it = 0; it < 24; ++it) {
    __syncthreads();
    *(float4*)((char*)As + ((wbase)      ^ sw)) = ra0;
    *(float4*)((char*)As + ((wbase + 16) ^ sw)) = ra1;
    *(float4*)((char*)Bs + ((wbase)      ^ sw)) = rbv0;
    *(float4*)((char*)Bs + ((wbase + 16) ^ sw)) = rbv1;
    __syncthreads();
    if (it < 23) MG_LOAD(it + 1);
    #pragma unroll
    for (int ks = 0; ks < 2; ++ks) {
      int kb2 = (ks*32 + ((lane >> 4) << 3))*2;
      int ar0 = wr*32 + (lane & 15), ar1 = ar0 + 16;
      int bc0 = wc*32 + (lane & 15), bc1 = bc0 + 16;
      s8v a0 = *(const s8v*)((const char*)As + ((ar0*128 + kb2) ^ ((ar0 & 7) << 4)));
      s8v a1 = *(const s8v*)((const char*)As + ((ar1*128 + kb2) ^ ((ar1 & 7) << 4)));
      s8v b0 = *(const s8v*)((const char*)Bs + ((bc0*128 + kb2) ^ ((bc0 & 7) << 4)));
      s8v b1 = *(const s8v*)((const char*)Bs + ((bc1*128 + kb2) ^ ((bc1 & 7) << 4)));
      acc00 = MFMA16(a0, b0, acc00, 0, 0, 0);
      acc01 = MFMA16(a0, b1, acc01, 0, 0, 0);
      acc10 = MFMA16(a1, b0, acc10, 0, 0, 0);
      acc11 = MFMA16(a1, b1, acc11, 0, 0, 0);
    }
  }
  #undef MG_LOAD
  int rr = (lane >> 4)*4, cc = lane & 15;
  {
    size_t rbase = (size_t)rb*64 + wr*32 + rr;
    int cbase = gy*64 + wc*32 + cc;
    #pragma unroll
    for (int u = 0; u < 4; ++u) {
      C[(rbase + u)*CO + cbase]           = acc00[u];
      C[(rbase + u)*CO + cbase + 16]      = acc01[u];
      C[(rbase + 16 + u)*CO + cbase]      = acc10[u];
      C[(rbase + 16 + u)*CO + cbase + 16] = acc11[u];
    }
  }
  // column partial sums / sumsq over the block's 64 rows
  {
    float s0 = 0.f, q0 = 0.f, s1 = 0.f, q1 = 0.f;
    #pragma unroll
    for (int u = 0; u < 4; ++u) {
      s0 += acc00[u] + acc10[u]; q0 += acc00[u]*acc00[u] + acc10[u]*acc10[u];
      s1 += acc01[u] + acc11[u]; q1 += acc01[u]*acc01[u] + acc11[u]*acc11[u];
    }
    s0 += __shfl_xor(s0, 16, 64); s0 += __shfl_xor(s0, 32, 64);
    q0 += __shfl_xor(q0, 16, 64); q0 += __shfl_xor(q0, 32, 64);
    s1 += __shfl_xor(s1, 16, 64); s1 += __shfl_xor(s1, 32, 64);
    q1 += __shfl_xor(q1, 16, 64); q1 += __shfl_xor(q1, 32, 64);
    if (lane < 16) {
      colS[w][wc*32 + cc] = s0;      colQ[w][wc*32 + cc] = q0;
      colS[w][wc*32 + 16 + cc] = s1; colQ[w][wc*32 + 16 + cc] = q1;
    }
  }
  __syncthreads();
  if (tid < 64) {
    int c = tid, wc2 = c >> 5;
    float s = colS[2*wc2][c] + colS[2*wc2+1][c];
    float qq = colQ[2*wc2][c] + colQ[2*wc2+1][c];
    outPart[((size_t)rb*CO + gy*64 + c)*2]     = s;
    outPart[((size_t)rb*CO + gy*64 + c)*2 + 1] = qq;
  }
}

// ---------------- MFMA gemm5: bn4+relu(a4) x conv5 -> partials only ----------------
__global__ __launch_bounds__(256) void k_g5(const float* __restrict__ A,
    const unsigned short* __restrict__ Bt, const float* __restrict__ bnc,
    float* __restrict__ outPart, float* __restrict__ outMax)
{
  __shared__ __align__(16) unsigned short As[4096];
  __shared__ __align__(16) unsigned short Bs[4096];
  __shared__ float colS[4][64], colQ[4][64], colM[4][64];
  __shared__ float scS[128], shS[128];
  int tid = threadIdx.x;
  int rb = blockIdx.x, gy = blockIdx.y;
  int w = tid >> 6, lane = tid & 63;
  int wr = w & 1, wc = w >> 1;
  int r = tid >> 2, q = tid & 3;
  if (tid < 128) { scS[tid] = bnc[tid]; shS[tid] = bnc[128 + tid]; }
  f32x4 acc00 = {0,0,0,0}, acc01 = {0,0,0,0}, acc10 = {0,0,0,0}, acc11 = {0,0,0,0};
  float4 va0, va1, va2, va3, rbv0, rbv1;
  #define G5_LOAD(IT) { int kk_ = ((IT) & 1) << 6; \
    const float4* ap_ = (const float4*)(A + (size_t)(rb*64 + r)*128 + kk_ + q*16); \
    va0 = ap_[0]; va1 = ap_[1]; va2 = ap_[2]; va3 = ap_[3]; \
    const float4* bp_ = (const float4*)(Bt + (size_t)(gy*64 + r)*384 + (size_t)(IT)*64 + q*16); \
    rbv0 = bp_[0]; rbv1 = bp_[1]; }
  G5_LOAD(0);
  int wbase = r*128 + q*32, sw = (r & 7) << 4;
  for (int it = 0; it < 6; ++it) {
    int p = it >> 1, kc = ((it & 1) << 6) + q*16;
    __syncthreads();
    {
      unsigned int pk[8];
      float vv[16] = {va0.x,va0.y,va0.z,va0.w, va1.x,va1.y,va1.z,va1.w,
                      va2.x,va2.y,va2.z,va2.w, va3.x,va3.y,va3.z,va3.w};
      #pragma unroll
      for (int j2 = 0; j2 < 8; ++j2) {
        float y0 = fmaxf(0.f, vv[2*j2]  *scS[kc + 2*j2]   + shS[kc + 2*j2]);
        float y1 = fmaxf(0.f, vv[2*j2+1]*scS[kc + 2*j2+1] + shS[kc + 2*j2+1]);
        unsigned short h0 = f2bf(y0), h1 = f2bf(y1);
        unsigned short o0 = (p == 1) ? f2bf(y0 - bf2f(h0)) : h0;
        unsigned short o1 = (p == 1) ? f2bf(y1 - bf2f(h1)) : h1;
        pk[j2] = (unsigned int)o0 | ((unsigned int)o1 << 16);
      }
      *(uint4*)((char*)As + ((wbase)      ^ sw)) = make_uint4(pk[0], pk[1], pk[2], pk[3]);
      *(uint4*)((char*)As + ((wbase + 16) ^ sw)) = make_uint4(pk[4], pk[5], pk[6], pk[7]);
      *(float4*)((char*)Bs + ((wbase)      ^ sw)) = rbv0;
      *(float4*)((char*)Bs + ((wbase + 16) ^ sw)) = rbv1;
    }
    __syncthreads();
    if (it < 5) G5_LOAD(it + 1);
    #pragma unroll
    for (int ks = 0; ks < 2; ++ks) {
      int kb2 = (ks*32 + ((lane >> 4) << 3))*2;
      int ar0 = wr*32 + (lane & 15), ar1 = ar0 + 16;
      int bc0 = wc*32 + (lane & 15), bc1 = bc0 + 16;
      s8v a0 = *(const s8v*)((const char*)As + ((ar0*128 + kb2) ^ ((ar0 & 7) << 4)));
      s8v a1 = *(const s8v*)((const char*)As + ((ar1*128 + kb2) ^ ((ar1 & 7) << 4)));
      s8v b0 = *(const s8v*)((const char*)Bs + ((bc0*128 + kb2) ^ ((bc0 & 7) << 4)));
      s8v b1 = *(const s8v*)((const char*)Bs + ((bc1*128 + kb2) ^ ((bc1 & 7) << 4)));
      acc00 = MFMA16(a0, b0, acc00, 0, 0, 0);
      acc01 = MFMA16(a0, b1, acc01, 0, 0, 0);
      acc10 = MFMA16(a1, b0, acc10, 0, 0, 0);
      acc11 = MFMA16(a1, b1, acc11, 0, 0, 0);
    }
  }
  #undef G5_LOAD
  int cc = lane & 15;
  {
    float s0=0.f,q0=0.f,m0=-3.4e38f, s1=0.f,q1=0.f,m1=-3.4e38f;
    #pragma unroll
    for (int u = 0; u < 4; ++u) {
      s0 += acc00[u] + acc10[u]; q0 += acc00[u]*acc00[u] + acc10[u]*acc10[u];
      m0 = fmaxf(m0, fmaxf(acc00[u], acc10[u]));
      s1 += acc01[u] + acc11[u]; q1 += acc01[u]*acc01[u] + acc11[u]*acc11[u];
      m1 = fmaxf(m1, fmaxf(acc01[u], acc11[u]));
    }
    s0 += __shfl_xor(s0, 16, 64); s0 += __shfl_xor(s0, 32, 64);
    q0 += __shfl_xor(q0, 16, 64); q0 += __shfl_xor(q0, 32, 64);
    m0 = fmaxf(m0, __shfl_xor(m0, 16, 64)); m0 = fmaxf(m0, __shfl_xor(m0, 32, 64));
    s1 += __shfl_xor(s1, 16, 64); s1 += __shfl_xor(s1, 32, 64);
    q1 += __shfl_xor(q1, 16, 64); q1 += __shfl_xor(q1, 32, 64);
    m1 = fmaxf(m1, __shfl_xor(m1, 16, 64)); m1 = fmaxf(m1, __shfl_xor(m1, 32, 64));
    if (lane < 16) {
      colS[w][wc*32 + cc] = s0;      colQ[w][wc*32 + cc] = q0;      colM[w][wc*32 + cc] = m0;
      colS[w][wc*32 + 16 + cc] = s1; colQ[w][wc*32 + 16 + cc] = q1; colM[w][wc*32 + 16 + cc] = m1;
    }
  }
  __syncthreads();
  if (tid < 64) {
    int c = tid, wc2 = c >> 5;
    float s = colS[2*wc2][c] + colS[2*wc2+1][c];
    float qq = colQ[2*wc2][c] + colQ[2*wc2+1][c];
    float m = fmaxf(colM[2*wc2][c], colM[2*wc2+1][c]);
    outPart[((size_t)rb*1024 + gy*64 + c)*2]     = s;
    outPart[((size_t)rb*1024 + gy*64 + c)*2 + 1] = qq;
    outMax[(size_t)rb*1024 + gy*64 + c] = m;
  }
}

// ---------------- bn5 + relu + maxpool over n ----------------
__global__ __launch_bounds__(256) void k_pool(const float* __restrict__ p5, const float* __restrict__ mx5,
    const float* __restrict__ g5, const float* __restrict__ b5, float* __restrict__ pool)
{
  int gid = blockIdx.x*256 + threadIdx.x;
  int b = gid >> 10, ch = gid & 1023;
  float s = 0.f, qq = 0.f;
  for (int rb = 0; rb < 128; ++rb) {
    s  += p5[((size_t)rb*1024 + ch)*2];
    qq += p5[((size_t)rb*1024 + ch)*2 + 1];
  }
  float mu = s / 8192.f;
  float var = qq / 8192.f - mu*mu;
  float rst = rsqrtf(var + EPS_);
  float mx = -3.4e38f;
  for (int t = 0; t < 16; ++t) mx = fmaxf(mx, mx5[(size_t)(b*16 + t)*1024 + ch]);
  pool[gid] = fmaxf(0.f, g5[ch]*(mx - mu)*rst + b5[ch]);
}

// ---------------- lin1: wave per output (4096 outputs) ----------------
__global__ __launch_bounds__(256) void k_lin1(const float* __restrict__ pool,
    const float* __restrict__ w, float* __restrict__ a6)
{
  int wid = threadIdx.x >> 6, lane = threadIdx.x & 63;
  int o = blockIdx.x*4 + wid;        // 0..4095
  int r = o >> 9, c = o & 511;
  const float4* pr = (const float4*)(pool + r*1024);
  const float4* wr = (const float4*)(w + (size_t)c*1024);
  float s = 0.f;
  #pragma unroll
  for (int t = 0; t < 4; ++t) {
    float4 a = pr[lane + 64*t], b = wr[lane + 64*t];
    s += a.x*b.x + a.y*b.y + a.z*b.z + a.w*b.w;
  }
  s = wredf(s);
  if (lane == 0) a6[o] = s;
}

// ---------------- head: wave per output (320 outputs), bn6 recomputed per lane ----------------
__global__ __launch_bounds__(256) void k_head(const float* __restrict__ a6,
    const float* __restrict__ g6, const float* __restrict__ b6,
    const float* __restrict__ w2, const float* __restrict__ bb,
    float* __restrict__ out)
{
  int wid = threadIdx.x >> 6, lane = threadIdx.x & 63;
  int o = blockIdx.x*4 + wid;        // 0..319
  int r = o / 40, c2 = o % 40;
  float s = 0.f;
  #pragma unroll
  for (int j = 0; j < 8; ++j) {
    int c = lane + 64*j;
    float sum = 0.f, vr = 0.f;
    float v[8];
    #pragma unroll
    for (int rr = 0; rr < 8; ++rr) { v[rr] = a6[rr*512 + c]; sum += v[rr]; }
    #pragma unroll
    for (int rr = 0; rr < 8; ++rr) vr = (rr == r) ? v[rr] : vr;
    float mu = sum / 8.f;
    float qq = 0.f;
    #pragma unroll
    for (int rr = 0; rr < 8; ++rr) { float d = v[rr] - mu; qq += d*d; }
    float rst = rsqrtf(qq / 8.f + EPS_);
    float f6r = fmaxf(0.f, (vr - mu)*g6[c]*rst + b6[c]);
    s += f6r * w2[c2*512 + c];
  }
  s = wredf(s);
  if (lane == 0) out[o] = s + bb[c2];
}

extern "C" void kernel_launch(void* const* d_in, const int* in_sizes, int n_in,
                              void* d_out, int out_size, void* d_ws, size_t ws_size,
                              hipStream_t stream) {
  (void)in_sizes; (void)n_in; (void)out_size; (void)ws_size;
  const float* x     = (const float*)d_in[0];
  const float* c1w   = (const float*)d_in[1];
  const float* bn1g  = (const float*)d_in[2];
  const float* bn1b  = (const float*)d_in[3];
  const float* mat2  = (const float*)d_in[4];
  const float* mat3  = (const float*)d_in[5];
  const float* mat4  = (const float*)d_in[6];
  const float* sn2w1 = (const float*)d_in[7];
  const float* sn2g  = (const float*)d_in[8];
  const float* sn2b  = (const float*)d_in[9];
  const float* sn2w2 = (const float*)d_in[10];
  const float* sn2b2 = (const float*)d_in[11];
  const float* sn3w1 = (const float*)d_in[12];
  const float* sn3g  = (const float*)d_in[13];
  const float* sn3b  = (const float*)d_in[14];
  const float* sn3w2 = (const float*)d_in[15];
  const float* sn3b2 = (const float*)d_in[16];
  const float* sn4w1 = (const float*)d_in[17];
  const float* sn4g  = (const float*)d_in[18];
  const float* sn4b  = (const float*)d_in[19];
  const float* sn4w2 = (const float*)d_in[20];
  const float* sn4b2 = (const float*)d_in[21];
  const float* bn2g  = (const float*)d_in[22];
  const float* bn2b  = (const float*)d_in[23];
  const float* bn3g  = (const float*)d_in[24];
  const float* bn3b  = (const float*)d_in[25];
  const float* bn4g  = (const float*)d_in[26];
  const float* bn4b  = (const float*)d_in[27];
  const float* c5w   = (const float*)d_in[28];
  const float* bn5g  = (const float*)d_in[29];
  const float* bn5b  = (const float*)d_in[30];
  const float* l1w   = (const float*)d_in[31];
  const float* bn6g  = (const float*)d_in[32];
  const float* bn6b  = (const float*)d_in[33];
  const float* l2w   = (const float*)d_in[34];
  const float* l2b   = (const float*)d_in[35];
  float* ws   = (float*)d_ws;
  float* f0   = ws + OFF_F0;
  int*   idxg = (int*)(ws + OFF_IDX);
  float* xyz  = ws + OFF_XYZ;
  float* hMom = ws + OFF_HM;
  float* b1P  = ws + OFF_B1P;
  float* mom42= ws + OFF_MOM;
  float* coef = ws + OFF_COEF;
  float* bn4c = ws + OFF_BN4C;
  unsigned short* W2  = (unsigned short*)(ws + OFF_W2);
  float* a2   = ws + OFF_A2;          // a3 aliases a2 (lifetimes disjoint)
  float* a4   = ws + OFF_A4;
  float* p2   = ws + OFF_P2;
  float* p3   = ws + OFF_P3;
  float* p4   = ws + OFF_P4;
  float* p5   = ws + OFF_P5;
  float* mx5  = ws + OFF_MX5;
  unsigned short* bt2 = (unsigned short*)(ws + OFF_BT2);
  unsigned short* bt3 = (unsigned short*)(ws + OFF_BT3);
  unsigned short* bt4 = (unsigned short*)(ws + OFF_BT4);
  unsigned short* bt5 = (unsigned short*)(ws + OFF_BT5);
  float* pool = ws + OFF_POOL;
  float* a6   = ws + OFF_A6;
  float* out  = (float*)d_out;

  k_prep<<<2048, 256, 0, stream>>>(x, c1w, idxg, xyz, f0);
  k_bsplit<<<3072, 256, 0, stream>>>(mat2, mat3, mat4, c5w, bt2, bt3, bt4, bt5);
  k_stats<<<192, 256, 0, stream>>>(xyz, f0, hMom, b1P);
  k_mom<<<1, 64, 0, stream>>>(hMom, mom42);

  k_coef<<<1, 128, 0, stream>>>(mom42, b1P, 32, sn2w1, sn2g, sn2b, bn1g, bn1b, coef);
  k_wbuild<<<2048, 256, 0, stream>>>(xyz, idxg, f0, coef, sn2w1, sn2w2, sn2b2, W2);
  k_mg<64><<<dim3(128, 1), 256, 0, stream>>>(W2, bt2, a2, p2);

  k_coef<<<1, 128, 0, stream>>>(mom42, p2, 128, sn3w1, sn3g, sn3b, bn2g, bn2b, coef);
  k_wbuild<<<2048, 256, 0, stream>>>(xyz, idxg, a2, coef, sn3w1, sn3w2, sn3b2, W2);
  k_mg<64><<<dim3(128, 1), 256, 0, stream>>>(W2, bt3, a2 /*a3*/, p3);

  k_coef<<<1, 128, 0, stream>>>(mom42, p3, 128, sn4w1, sn4g, sn4b, bn3g, bn3b, coef);
  k_wbuild<<<2048, 256, 0, stream>>>(xyz, idxg, a2 /*a3*/, coef, sn4w1, sn4w2, sn4b2, W2);
  k_mg<128><<<dim3(128, 2), 256, 0, stream>>>(W2, bt4, a4, p4);

  k_bnc<<<1, 128, 0, stream>>>(p4, bn4g, bn4b, bn4c);
  k_g5<<<dim3(128, 16), 256, 0, stream>>>(a4, bt5, bn4c, p5, mx5);

  k_pool<<<32, 256, 0, stream>>>(p5, mx5, bn5g, bn5b, pool);
  k_lin1<<<1024, 256, 0, stream>>>(pool, l1w, a6);
  k_head<<<80, 256, 0, stream>>>(a6, bn6g, bn6b, l2w, l2b, out);
}